// Round 1
// baseline (75.488 us; speedup 1.0000x reference)
//
#include <hip/hip_runtime.h>
#include <math.h>

namespace {

constexpr int L    = 64;    // steps
constexpr int NH   = 256;   // nhid
constexpr int NC   = 64;    // cache_N
constexpr int BSZ  = 32;
constexpr int BK   = 32;    // k-tile
constexpr int LDSS = 68;    // padded LDS stride (68*4B = 272B, 16B-aligned per row)

// One block per (b, n): C = Q_b (64x256) * K_{n,b}^T (256x64), output max(C).
__global__ __launch_bounds__(256, 4) void attmax_kernel(
    const float* __restrict__ query,   // (1, 64, 32, 256)
    const float* __restrict__ keys,    // (64, 32, 16384)
    float* __restrict__ out)           // out[0..2047] = att[b*64+n]
{
  __shared__ __align__(16) float Qs[BK * LDSS];   // Qs[kk][i], k-major
  __shared__ __align__(16) float Ks[BK * LDSS];   // Ks[kk][j], k-major
  __shared__ float wmax[4];

  const int tid = threadIdx.x;
  const int n = blockIdx.x & 63;
  const int b = blockIdx.x >> 6;

  const int i0 = (tid >> 4) * 4;   // 16x16 thread grid, 4x4 tile each
  const int j0 = (tid & 15) * 4;

  float acc[4][4];
#pragma unroll
  for (int a = 0; a < 4; ++a)
#pragma unroll
    for (int c = 0; c < 4; ++c) acc[a][c] = 0.f;

  // q element (i,h): query[(i*32 + b)*256 + h]
  const float* qbase = query + (size_t)b * NH;
  // k element (j,h): keys[((n*32 + b)*16384) + j*256 + h]
  const float* kbase = keys + ((size_t)n * BSZ + b) * (size_t)(L * NH);

  // staging: thread -> (row sr, float4-col sc) ; 2 rows per thread per matrix
  const int sr = tid >> 3;        // 0..31
  const int sc = (tid & 7) * 4;   // 0,4,...,28

  for (int h0 = 0; h0 < NH; h0 += BK) {
    __syncthreads();   // previous tile fully consumed before overwrite
#pragma unroll
    for (int p = 0; p < 2; ++p) {
      const int r = sr + p * 32;
      const float4 qv = *(const float4*)(qbase + (size_t)r * (BSZ * NH) + h0 + sc);
      const float4 kv = *(const float4*)(kbase + (size_t)r * NH + h0 + sc);
      Qs[(sc + 0) * LDSS + r] = qv.x;
      Qs[(sc + 1) * LDSS + r] = qv.y;
      Qs[(sc + 2) * LDSS + r] = qv.z;
      Qs[(sc + 3) * LDSS + r] = qv.w;
      Ks[(sc + 0) * LDSS + r] = kv.x;
      Ks[(sc + 1) * LDSS + r] = kv.y;
      Ks[(sc + 2) * LDSS + r] = kv.z;
      Ks[(sc + 3) * LDSS + r] = kv.w;
    }
    __syncthreads();
#pragma unroll
    for (int kk = 0; kk < BK; ++kk) {
      const float4 a4 = *(const float4*)&Qs[kk * LDSS + i0];  // 16B aligned
      const float4 b4 = *(const float4*)&Ks[kk * LDSS + j0];
      const float av[4] = {a4.x, a4.y, a4.z, a4.w};
      const float bv[4] = {b4.x, b4.y, b4.z, b4.w};
#pragma unroll
      for (int a = 0; a < 4; ++a)
#pragma unroll
        for (int c = 0; c < 4; ++c)
          acc[a][c] = fmaf(av[a], bv[c], acc[a][c]);
    }
  }

  // max over this thread's 4x4 tile
  float m = acc[0][0];
#pragma unroll
  for (int a = 0; a < 4; ++a)
#pragma unroll
    for (int c = 0; c < 4; ++c) m = fmaxf(m, acc[a][c]);

  // wave (64-lane) butterfly max
#pragma unroll
  for (int off = 1; off < 64; off <<= 1)
    m = fmaxf(m, __shfl_xor(m, off, 64));

  if ((tid & 63) == 0) wmax[tid >> 6] = m;
  __syncthreads();
  if (tid == 0) {
    out[(size_t)b * NC + n] =
        fmaxf(fmaxf(wmax[0], wmax[1]), fmaxf(wmax[2], wmax[3]));
  }
}

// One block (64 lanes) per batch b: 8 rounds of argmax with lowest-index
// tie-break (matches jax.lax.top_k stability). Indices written as floats.
__global__ __launch_bounds__(64) void topk_kernel(float* __restrict__ out) {
  const int b = blockIdx.x;
  const int l = threadIdx.x;
  float v = out[b * NC + l];
#pragma unroll
  for (int k = 0; k < 8; ++k) {
    float bv = v;
    int bi = l;
#pragma unroll
    for (int off = 1; off < 64; off <<= 1) {
      const float ov = __shfl_xor(bv, off, 64);
      const int oi = __shfl_xor(bi, off, 64);
      if (ov > bv || (ov == bv && oi < bi)) { bv = ov; bi = oi; }
    }
    if (l == 0) out[BSZ * NC + k * BSZ + b] = (float)bi;  // (topk, bsz) layout
    if (l == bi) v = -INFINITY;
  }
}

}  // namespace

extern "C" void kernel_launch(void* const* d_in, const int* in_sizes, int n_in,
                              void* d_out, int out_size, void* d_ws, size_t ws_size,
                              hipStream_t stream) {
  const float* query = (const float*)d_in[0];
  const float* keys  = (const float*)d_in[1];
  // d_in[2] (values) is dead code in the max_pooling branch — never read.
  float* out = (float*)d_out;

  attmax_kernel<<<dim3(BSZ * NC), dim3(256), 0, stream>>>(query, keys, out);
  topk_kernel<<<dim3(BSZ), dim3(64), 0, stream>>>(out);
}

// Round 3
// 46.679 us; speedup vs baseline: 1.6172x; 1.6172x over previous
//
#include <hip/hip_runtime.h>
#include <math.h>

namespace {

constexpr int L   = 64;    // steps
constexpr int NH  = 256;   // nhid
constexpr int NC  = 64;    // cache_N
constexpr int BSZ = 32;

typedef float f32x16 __attribute__((ext_vector_type(16)));
typedef short bf16x8 __attribute__((ext_vector_type(8)));   // 8 bf16 in 4 VGPRs
typedef unsigned int u32x4 __attribute__((ext_vector_type(4)));

// fp32 -> bf16 with round-to-nearest-even (bit pattern in low 16 of result).
// Inputs here are finite/normal; no NaN handling needed.
__device__ inline unsigned bf16_rne(float x) {
  const unsigned u = __builtin_bit_cast(unsigned, x);
  return (u + 0x7fffu + ((u >> 16) & 1u)) >> 16;
}

// Split 8 fp32 (two float4) into hi/lo bf16x8 fragments: x = hi + lo + O(2^-18 x)
__device__ inline void split8(const float4 x0, const float4 x1,
                              bf16x8& hi, bf16x8& lo) {
  float f[8];
  *(float4*)(f)     = x0;
  *(float4*)(f + 4) = x1;
  u32x4 hw, lw;
#pragma unroll
  for (int q = 0; q < 4; ++q) {
    const unsigned h0 = bf16_rne(f[2 * q]);
    const unsigned h1 = bf16_rne(f[2 * q + 1]);
    const float r0 = f[2 * q]     - __builtin_bit_cast(float, h0 << 16);
    const float r1 = f[2 * q + 1] - __builtin_bit_cast(float, h1 << 16);
    hw[q] = h0 | (h1 << 16);
    lw[q] = bf16_rne(r0) | (bf16_rne(r1) << 16);
  }
  hi = __builtin_bit_cast(bf16x8, hw);
  lo = __builtin_bit_cast(bf16x8, lw);
}

// One wave per (b, n): C(64x64) = Q_b(64x256) . K_{n,b}(64x256)^T via
// split-bf16 MFMA (3 passes), then max-reduce. No LDS. C layout irrelevant.
__global__ __launch_bounds__(64) void attmax_mfma(
    const float* __restrict__ query,   // (1, 64, 32, 256)
    const float* __restrict__ keys,    // (64, 32, 16384)
    float* __restrict__ out)           // out[b*64+n] = att
{
  const int n    = blockIdx.x & 63;
  const int b    = blockIdx.x >> 6;
  const int lane = threadIdx.x;      // 0..63
  const int r    = lane & 31;        // row within 32-tile
  const int h8   = (lane >> 5) * 8;  // k-subrange selector

  // Q element (i,k): query[(i*32 + b)*256 + k]   (row stride 32 KB)
  // K element (j,k): keys[(n*32 + b)*16384 + j*256 + k]  (row stride 1 KB)
  const float* qb = query + (size_t)b * NH;
  const float* kb = keys + ((size_t)n * BSZ + b) * (size_t)(L * NH);

  f32x16 acc[2][2];
#pragma unroll
  for (int i = 0; i < 2; ++i)
#pragma unroll
    for (int j = 0; j < 2; ++j)
#pragma unroll
      for (int e = 0; e < 16; ++e) acc[i][j][e] = 0.f;

#pragma unroll 2
  for (int kc = 0; kc < NH; kc += 16) {
    // Issue all 8 global loads first (32 B/lane per matrix tile), then convert.
    float4 xq[2][2], xk[2][2];
#pragma unroll
    for (int t = 0; t < 2; ++t) {
      const float* qs = qb + (size_t)(t * 32 + r) * (BSZ * NH) + kc + h8;
      const float* ks = kb + (size_t)(t * 32 + r) * NH + kc + h8;
      xq[t][0] = *(const float4*)(qs);
      xq[t][1] = *(const float4*)(qs + 4);
      xk[t][0] = *(const float4*)(ks);
      xk[t][1] = *(const float4*)(ks + 4);
    }
    bf16x8 ah[2], al[2], bh[2], bl[2];
#pragma unroll
    for (int t = 0; t < 2; ++t) {
      split8(xq[t][0], xq[t][1], ah[t], al[t]);
      split8(xk[t][0], xk[t][1], bh[t], bl[t]);
    }
#pragma unroll
    for (int i = 0; i < 2; ++i)
#pragma unroll
      for (int j = 0; j < 2; ++j) {
        acc[i][j] = __builtin_amdgcn_mfma_f32_32x32x16_bf16(al[i], bh[j], acc[i][j], 0, 0, 0);
        acc[i][j] = __builtin_amdgcn_mfma_f32_32x32x16_bf16(ah[i], bl[j], acc[i][j], 0, 0, 0);
        acc[i][j] = __builtin_amdgcn_mfma_f32_32x32x16_bf16(ah[i], bh[j], acc[i][j], 0, 0, 0);
      }
  }

  float m = -INFINITY;
#pragma unroll
  for (int i = 0; i < 2; ++i)
#pragma unroll
    for (int j = 0; j < 2; ++j)
#pragma unroll
      for (int e = 0; e < 16; ++e) m = fmaxf(m, acc[i][j][e]);

#pragma unroll
  for (int off = 1; off < 64; off <<= 1)
    m = fmaxf(m, __shfl_xor(m, off, 64));

  if (lane == 0) out[(size_t)b * NC + n] = m;
}

// One block (64 lanes) per batch b: 8 rounds of argmax with lowest-index
// tie-break (matches jax.lax.top_k stability). Indices written as floats.
__global__ __launch_bounds__(64) void topk_kernel(float* __restrict__ out) {
  const int b = blockIdx.x;
  const int l = threadIdx.x;
  float v = out[b * NC + l];
#pragma unroll
  for (int k = 0; k < 8; ++k) {
    float bv = v;
    int bi = l;
#pragma unroll
    for (int off = 1; off < 64; off <<= 1) {
      const float ov = __shfl_xor(bv, off, 64);
      const int oi = __shfl_xor(bi, off, 64);
      if (ov > bv || (ov == bv && oi < bi)) { bv = ov; bi = oi; }
    }
    if (l == 0) out[BSZ * NC + k * BSZ + b] = (float)bi;  // (topk, bsz) layout
    if (l == bi) v = -INFINITY;
  }
}

}  // namespace

extern "C" void kernel_launch(void* const* d_in, const int* in_sizes, int n_in,
                              void* d_out, int out_size, void* d_ws, size_t ws_size,
                              hipStream_t stream) {
  const float* query = (const float*)d_in[0];
  const float* keys  = (const float*)d_in[1];
  // d_in[2] (values) is dead code in the max_pooling branch — never read.
  float* out = (float*)d_out;

  attmax_mfma<<<dim3(BSZ * NC), dim3(64), 0, stream>>>(query, keys, out);
  topk_kernel<<<dim3(BSZ), dim3(64), 0, stream>>>(out);
}